// Round 1
// baseline (859.863 us; speedup 1.0000x reference)
//
#include <hip/hip_runtime.h>
#include <hip/hip_bf16.h>

#define LOG2E 1.4426950408889634f
#define LN2   0.6931471805599453f

typedef __attribute__((ext_vector_type(8))) short short8;
typedef __attribute__((ext_vector_type(4))) float f32x4;

#define B_ 8
#define N_ 128
#define M_ 32
#define C_ 65536
#define KCHUNKS 64
#define KC (C_ / KCHUNKS)   // 1024
#define BK 64
#define AST 72              // LDS row stride in bf16 elems (144B: 16B-aligned, bank-even)

__device__ __forceinline__ unsigned short f2bf(float f) {
  unsigned u = __builtin_bit_cast(unsigned, f);
  u += 0x7fffu + ((u >> 16) & 1u);   // RNE
  return (unsigned short)(u >> 16);
}

// Fused: load pred tile -> compute x, sigmoid, softplus -> bf16 LDS tiles ->
// MFMA vs gt tile. Accumulate xg = x.gt^T and sg = s.gt^T partials + row sums.
__global__ __launch_bounds__(256, 2) void cost_partial_kernel(
    const float* __restrict__ pred, const float* __restrict__ gt,
    float* __restrict__ xg, float* __restrict__ sg,
    float* __restrict__ spsum, float* __restrict__ ssum,
    float* __restrict__ gtsum)
{
  __shared__ unsigned short As[256 * AST];  // rows 0..127: x, 128..255: sigmoid
  __shared__ unsigned short Bt[32 * AST];   // gt tile
  const int kc = blockIdx.x, b = blockIdx.y;
  const int tid = threadIdx.x;
  const int grp = tid >> 4, gl = tid & 15;
  const int wave = tid >> 6, lane = tid & 63;
  const int c0 = kc * KC;

  const float* predB = pred + (size_t)b * N_ * C_;
  const float* gtB   = gt   + (size_t)b * M_ * C_;

  float sp_part[8], s_part[8], gts_part[2];
#pragma unroll
  for (int r = 0; r < 8; ++r) { sp_part[r] = 0.f; s_part[r] = 0.f; }
  gts_part[0] = 0.f; gts_part[1] = 0.f;

  f32x4 acc[4][2];
#pragma unroll
  for (int rt = 0; rt < 4; ++rt)
#pragma unroll
    for (int ct = 0; ct < 2; ++ct)
      acc[rt][ct] = (f32x4){0.f, 0.f, 0.f, 0.f};

  for (int ks = 0; ks < KC / BK; ++ks) {
    const int cbase = c0 + ks * BK;
    // ---- stage pred -> x(bf16), s(bf16); accumulate softplus/sigmoid sums
#pragma unroll
    for (int r = 0; r < 8; ++r) {
      const int row = r * 16 + grp;
      const float4 p = *(const float4*)(predB + (size_t)row * C_ + cbase + gl * 4);
      float xs[4] = {p.x, p.y, p.z, p.w};
      unsigned short xo[4], so[4];
#pragma unroll
      for (int e = 0; e < 4; ++e) {
        float x = xs[e];
        float t = fminf(fmaxf(x * LOG2E, -80.f), 80.f);
        float e2 = __builtin_amdgcn_exp2f(t);
        float z = 1.f + e2;
        float s = e2 * __builtin_amdgcn_rcpf(z);
        float sp = __builtin_amdgcn_logf(z) * LN2;   // log1p(exp(x))
        sp_part[r] += sp;
        s_part[r]  += s;
        xo[e] = f2bf(x);
        so[e] = f2bf(s);
      }
      *(ushort4*)&As[row * AST + gl * 4]        = make_ushort4(xo[0], xo[1], xo[2], xo[3]);
      *(ushort4*)&As[(N_ + row) * AST + gl * 4] = make_ushort4(so[0], so[1], so[2], so[3]);
    }
    // ---- stage gt -> bf16; accumulate gt sums
#pragma unroll
    for (int q = 0; q < 2; ++q) {
      const int m = q * 16 + grp;
      const float4 g = *(const float4*)(gtB + (size_t)m * C_ + cbase + gl * 4);
      gts_part[q] += g.x + g.y + g.z + g.w;
      *(ushort4*)&Bt[m * AST + gl * 4] = make_ushort4(f2bf(g.x), f2bf(g.y), f2bf(g.z), f2bf(g.w));
    }
    __syncthreads();
    // ---- MFMA: out rows = wave*64 + rt*16 + (lane&15), cols = ct*16 + (lane&15)
#pragma unroll
    for (int k0 = 0; k0 < BK; k0 += 32) {
      const int koff = k0 + (lane >> 4) * 8;
      short8 bfr0 = *(const short8*)&Bt[(lane & 15) * AST + koff];
      short8 bfr1 = *(const short8*)&Bt[(16 + (lane & 15)) * AST + koff];
#pragma unroll
      for (int rt = 0; rt < 4; ++rt) {
        short8 af = *(const short8*)&As[(wave * 64 + rt * 16 + (lane & 15)) * AST + koff];
        acc[rt][0] = __builtin_amdgcn_mfma_f32_16x16x32_bf16(af, bfr0, acc[rt][0], 0, 0, 0);
        acc[rt][1] = __builtin_amdgcn_mfma_f32_16x16x32_bf16(af, bfr1, acc[rt][1], 0, 0, 0);
      }
    }
    __syncthreads();
  }

  // ---- row-sum reductions (16 threads with same grp share a row)
#pragma unroll
  for (int r = 0; r < 8; ++r) {
    float v1 = sp_part[r], v2 = s_part[r];
#pragma unroll
    for (int off = 1; off < 16; off <<= 1) {
      v1 += __shfl_xor(v1, off);
      v2 += __shfl_xor(v2, off);
    }
    if (gl == 0) {
      const int row = r * 16 + grp;
      atomicAdd(&spsum[b * N_ + row], v1);
      atomicAdd(&ssum[b * N_ + row], v2);
    }
  }
#pragma unroll
  for (int q = 0; q < 2; ++q) {
    float v = gts_part[q];
#pragma unroll
    for (int off = 1; off < 16; off <<= 1) v += __shfl_xor(v, off);
    if (gl == 0) atomicAdd(&gtsum[b * M_ + q * 16 + grp], v);
  }
  // ---- GEMM partials: C/D layout col=lane&15, row=(lane>>4)*4+reg
  const int quad = lane >> 4, lcol = lane & 15;
#pragma unroll
  for (int rt = 0; rt < 4; ++rt)
#pragma unroll
    for (int ct = 0; ct < 2; ++ct)
#pragma unroll
      for (int reg = 0; reg < 4; ++reg) {
        int orow = wave * 64 + rt * 16 + quad * 4 + reg;
        int ocol = ct * 16 + lcol;
        float v = acc[rt][ct][reg];
        if (orow < N_) atomicAdd(&xg[(b * N_ + orow) * M_ + ocol], v);
        else           atomicAdd(&sg[(b * N_ + (orow - N_)) * M_ + ocol], v);
      }
}

__global__ void finalize_kernel(const float* __restrict__ obj,
    const float* __restrict__ xg, const float* __restrict__ sg,
    const float* __restrict__ spsum, const float* __restrict__ ssum,
    const float* __restrict__ gtsum, float* __restrict__ cost)
{
  int idx = blockIdx.x * blockDim.x + threadIdx.x;  // [0, 32768)
  int b = idx >> 12;
  int n = (idx >> 5) & 127;
  int m = idx & 31;
  float o = obj[b * N_ + n];
  float t = fminf(fmaxf(o * LOG2E, -80.f), 80.f);
  float e2 = __builtin_amdgcn_exp2f(t);
  float sig = e2 * __builtin_amdgcn_rcpf(1.f + e2);
  float bce = (spsum[b * N_ + n] - xg[idx]) * (1.0f / (float)C_);
  float dice = 1.f - (2.f * sg[idx] + 1.f) / (ssum[b * N_ + n] + gtsum[b * M_ + m] + 1.f);
  cost[idx] = -2.f * sig + 5.f * bce + 5.f * dice;
}

#define BIG 1e30f

// Jonker-Volgenant shortest augmenting path on cost^T [32 x 128], one wave per batch.
// Lane owns columns j=lane and j=lane+64 (v, shortest, path, SC in registers).
__global__ __launch_bounds__(64) void lsap_kernel(const float* __restrict__ cost,
                                                  float* __restrict__ out)
{
  const int b = blockIdx.x;
  const int lane = threadIdx.x;
  __shared__ float cT[M_][N_];
  __shared__ float u[M_];
  __shared__ int col4row[M_];

  for (int idx = lane; idx < N_ * M_; idx += 64) {
    // enumerate cT linearly -> conflict-free LDS writes; gathered L2 reads
    int m = idx >> 7, n = idx & 127;
    cT[m][n] = cost[b * N_ * M_ + n * M_ + m];
  }
  if (lane < M_) { u[lane] = 0.f; col4row[lane] = -1; }
  float v0 = 0.f, v1 = 0.f;
  int r40 = -1, r41 = -1;   // row4col for owned columns
  __syncthreads();

  for (int cur = 0; cur < M_; ++cur) {
    float sh0 = BIG, sh1 = BIG;
    int p0 = -1, p1 = -1;
    bool c0 = false, c1 = false;
    unsigned srmask = 0;
    int i = cur, sink = -1;
    float minVal = 0.f;
    while (sink < 0) {
      srmask |= (1u << i);
      float ui = u[i];
      float base = minVal - ui;
      float d0 = base + cT[i][lane] - v0;
      float d1 = base + cT[i][lane + 64] - v1;
      if (!c0 && d0 < sh0) { sh0 = d0; p0 = i; }
      if (!c1 && d1 < sh1) { sh1 = d1; p1 = i; }
      float m0 = c0 ? BIG : sh0;
      float m1 = c1 ? BIG : sh1;
      float val; int jdx;
      if (m1 < m0) { val = m1; jdx = lane + 64; }
      else         { val = m0; jdx = lane; }
#pragma unroll
      for (int off = 1; off < 64; off <<= 1) {  // argmin, first-index tie-break
        float ov = __shfl_xor(val, off);
        int   oj = __shfl_xor(jdx, off);
        if (ov < val || (ov == val && oj < jdx)) { val = ov; jdx = oj; }
      }
      minVal = val;
      int j = jdx;
      if (j < 64) { if (lane == j) c0 = true; }
      else        { if (lane == j - 64) c1 = true; }
      int nj0 = __shfl(r40, j & 63);
      int nj1 = __shfl(r41, j & 63);
      int nxt = (j < 64) ? nj0 : nj1;
      if (nxt < 0) sink = j; else i = nxt;
    }
    // dual updates (before augmentation, as in scipy)
    int jj = (lane < M_) ? col4row[lane] : 0;
    int jjc = jj < 0 ? 0 : jj;
    float g0 = __shfl(sh0, jjc & 63);
    float g1 = __shfl(sh1, jjc & 63);
    float sj = (jjc < 64) ? g0 : g1;
    __syncthreads();
    if (lane < M_) {
      if (lane == cur) u[lane] += minVal;
      else if ((srmask >> lane) & 1u) u[lane] += minVal - sj;
    }
    if (c0) v0 -= minVal - sh0;
    if (c1) v1 -= minVal - sh1;
    __syncthreads();
    // augment along path
    int j = sink;
    while (true) {
      int a0 = __shfl(p0, j & 63);
      int a1 = __shfl(p1, j & 63);
      int i2 = (j < 64) ? a0 : a1;
      if (j < 64) { if (lane == j) r40 = i2; }
      else        { if (lane == j - 64) r41 = i2; }
      int tmp = col4row[i2];
      __syncthreads();
      if (lane == 0) col4row[i2] = j;
      __syncthreads();
      if (i2 == cur) break;
      j = tmp;
    }
  }
  if (lane < M_) out[b * M_ + lane] = (float)col4row[lane];
}

extern "C" void kernel_launch(void* const* d_in, const int* in_sizes, int n_in,
                              void* d_out, int out_size, void* d_ws, size_t ws_size,
                              hipStream_t stream)
{
  const float* obj  = (const float*)d_in[0];   // [8,128]
  const float* pred = (const float*)d_in[1];   // [8,128,65536]
  const float* gt   = (const float*)d_in[2];   // [8,32,65536]
  float* out = (float*)d_out;                  // cost 32768 || indices 256 (as float)

  float* xg    = (float*)d_ws;      // 32768
  float* sg    = xg + 32768;        // 32768
  float* spsum = sg + 32768;        // 1024
  float* ssum  = spsum + 1024;      // 1024
  float* gtsum = ssum + 1024;       // 256

  hipMemsetAsync(d_ws, 0, (size_t)(32768 * 2 + 1024 * 2 + 256) * sizeof(float), stream);
  cost_partial_kernel<<<dim3(KCHUNKS, B_), 256, 0, stream>>>(pred, gt, xg, sg, spsum, ssum, gtsum);
  finalize_kernel<<<dim3(32768 / 256), 256, 0, stream>>>(obj, xg, sg, spsum, ssum, gtsum, out);
  lsap_kernel<<<dim3(B_), 64, 0, stream>>>(out, out + 32768);
}

// Round 2
// 569.468 us; speedup vs baseline: 1.5099x; 1.5099x over previous
//
#include <hip/hip_runtime.h>
#include <hip/hip_bf16.h>

#define LOG2E 1.4426950408889634f
#define LN2   0.6931471805599453f

typedef __attribute__((ext_vector_type(8))) short short8;
typedef __attribute__((ext_vector_type(4))) float f32x4;

#define B_ 8
#define N_ 128
#define M_ 32
#define C_ 65536
#define KCHUNKS 32
#define KC (C_ / KCHUNKS)   // 2048
#define BK 128
#define AST 136             // LDS row stride in bf16 elems (272B: 16B-aligned, 4-bank rotate/row)

__device__ __forceinline__ unsigned short f2bf(float f) {
  unsigned u = __builtin_bit_cast(unsigned, f);
  u += 0x7fffu + ((u >> 16) & 1u);   // RNE
  return (unsigned short)(u >> 16);
}
__device__ __forceinline__ unsigned pack_rne(float lo, float hi) {
  return (unsigned)f2bf(lo) | ((unsigned)f2bf(hi) << 16);
}
__device__ __forceinline__ unsigned pack_trunc(float lo, float hi) {  // exact for {0,1}
  unsigned ul = __builtin_bit_cast(unsigned, lo);
  unsigned uh = __builtin_bit_cast(unsigned, hi);
  return (uh & 0xFFFF0000u) | (ul >> 16);
}

// 256 blocks x 512 threads. Block = (kc slice of 2048 cols) x batch.
// Thread owns one pred row (4 threads/row x 8 float4 = 128 cols/iter).
// Wave w<4: x-GEMM rows w*32..w*32+31; w>=4: s-GEMM rows (w-4)*32...
__global__ __launch_bounds__(512, 2) void cost_partial_kernel(
    const float* __restrict__ pred, const float* __restrict__ gt,
    float* __restrict__ xg, float* __restrict__ sg,
    float* __restrict__ spsum, float* __restrict__ ssum,
    float* __restrict__ gtsum)
{
  __shared__ unsigned short Asx[128 * AST];
  __shared__ unsigned short Ass[128 * AST];
  __shared__ unsigned short Bt[32 * AST];
  const int kc = blockIdx.x, b = blockIdx.y;
  const int tid = threadIdx.x;
  const int lane = tid & 63;
  const int wave = tid >> 6;
  const int quad = lane >> 4, lcol = lane & 15;
  const int prow = tid >> 2, pq = tid & 3;   // pred row, quarter
  const int grow = tid >> 4, gh = tid & 15;  // gt row, sixteenth
  const int c0 = kc * KC;

  const float* predB = pred + (size_t)b * N_ * C_ + (size_t)prow * C_ + c0;
  const float* gtB   = gt   + (size_t)b * M_ * C_ + (size_t)grow * C_ + c0;

  float spacc = 0.f, sacc = 0.f, gtacc = 0.f;
  f32x4 acc[2][2];
#pragma unroll
  for (int rt = 0; rt < 2; ++rt)
#pragma unroll
    for (int ct = 0; ct < 2; ++ct)
      acc[rt][ct] = (f32x4){0.f, 0.f, 0.f, 0.f};

  for (int ks = 0; ks < KC / BK; ++ks) {
    const int cb = ks * BK;
    float4 p[8];
#pragma unroll
    for (int i = 0; i < 8; ++i)
      p[i] = *(const float4*)(predB + cb + (i * 4 + pq) * 4);
    float4 g0 = *(const float4*)(gtB + cb + gh * 4);
    float4 g1 = *(const float4*)(gtB + cb + (gh + 16) * 4);

#pragma unroll
    for (int i = 0; i < 8; ++i) {
      float xs[4] = {p[i].x, p[i].y, p[i].z, p[i].w};
      float ss[4];
#pragma unroll
      for (int e = 0; e < 4; ++e) {
        float x = xs[e];
        float t = fminf(fmaxf(x * LOG2E, -80.f), 80.f);
        float e2 = __builtin_amdgcn_exp2f(t);
        float z = 1.f + e2;
        float s = e2 * __builtin_amdgcn_rcpf(z);
        spacc += __builtin_amdgcn_logf(z) * LN2;
        sacc += s;
        ss[e] = s;
      }
      uint2 ux = {pack_rne(xs[0], xs[1]), pack_rne(xs[2], xs[3])};
      uint2 us = {pack_rne(ss[0], ss[1]), pack_rne(ss[2], ss[3])};
      *(uint2*)&Asx[prow * AST + (i * 4 + pq) * 4] = ux;
      *(uint2*)&Ass[prow * AST + (i * 4 + pq) * 4] = us;
    }
    gtacc += g0.x + g0.y + g0.z + g0.w + g1.x + g1.y + g1.z + g1.w;
    *(uint2*)&Bt[grow * AST + gh * 4]      = (uint2){pack_trunc(g0.x, g0.y), pack_trunc(g0.z, g0.w)};
    *(uint2*)&Bt[grow * AST + 64 + gh * 4] = (uint2){pack_trunc(g1.x, g1.y), pack_trunc(g1.z, g1.w)};
    __syncthreads();

    const unsigned short* Abase = (wave < 4) ? &Asx[(wave * 32) * AST]
                                             : &Ass[((wave - 4) * 32) * AST];
#pragma unroll
    for (int k0 = 0; k0 < BK; k0 += 32) {
      const int koff = k0 + quad * 8;
      short8 bf0 = *(const short8*)&Bt[lcol * AST + koff];
      short8 bf1 = *(const short8*)&Bt[(16 + lcol) * AST + koff];
#pragma unroll
      for (int rt = 0; rt < 2; ++rt) {
        short8 af = *(const short8*)&Abase[(rt * 16 + lcol) * AST + koff];
        acc[rt][0] = __builtin_amdgcn_mfma_f32_16x16x32_bf16(af, bf0, acc[rt][0], 0, 0, 0);
        acc[rt][1] = __builtin_amdgcn_mfma_f32_16x16x32_bf16(af, bf1, acc[rt][1], 0, 0, 0);
      }
    }
    __syncthreads();
  }

  // per-row sums: 4 lanes share a pred row; 16 lanes share a gt row
  spacc += __shfl_xor(spacc, 1); spacc += __shfl_xor(spacc, 2);
  sacc  += __shfl_xor(sacc, 1);  sacc  += __shfl_xor(sacc, 2);
  if (pq == 0) {
    atomicAdd(&spsum[b * N_ + prow], spacc);
    atomicAdd(&ssum[b * N_ + prow], sacc);
  }
  gtacc += __shfl_xor(gtacc, 1); gtacc += __shfl_xor(gtacc, 2);
  gtacc += __shfl_xor(gtacc, 4); gtacc += __shfl_xor(gtacc, 8);
  if (gh == 0) atomicAdd(&gtsum[b * M_ + grow], gtacc);

  // GEMM partials: C/D layout col=lane&15, row=(lane>>4)*4+reg
#pragma unroll
  for (int rt = 0; rt < 2; ++rt)
#pragma unroll
    for (int ct = 0; ct < 2; ++ct)
#pragma unroll
      for (int reg = 0; reg < 4; ++reg) {
        int r = (wave & 3) * 32 + rt * 16 + quad * 4 + reg;
        int ocol = ct * 16 + lcol;
        float v = acc[rt][ct][reg];
        float* dst = (wave < 4) ? xg : sg;
        atomicAdd(&dst[(b * N_ + r) * M_ + ocol], v);
      }
}

__global__ void finalize_kernel(const float* __restrict__ obj,
    const float* __restrict__ xg, const float* __restrict__ sg,
    const float* __restrict__ spsum, const float* __restrict__ ssum,
    const float* __restrict__ gtsum, float* __restrict__ cost)
{
  int idx = blockIdx.x * blockDim.x + threadIdx.x;  // [0, 32768)
  int b = idx >> 12;
  int n = (idx >> 5) & 127;
  int m = idx & 31;
  float o = obj[b * N_ + n];
  float t = fminf(fmaxf(o * LOG2E, -80.f), 80.f);
  float e2 = __builtin_amdgcn_exp2f(t);
  float sig = e2 * __builtin_amdgcn_rcpf(1.f + e2);
  float bce = (spsum[b * N_ + n] - xg[idx]) * (1.0f / (float)C_);
  float dice = 1.f - (2.f * sg[idx] + 1.f) / (ssum[b * N_ + n] + gtsum[b * M_ + m] + 1.f);
  cost[idx] = -2.f * sig + 5.f * bce + 5.f * dice;
}

#define BIGF 1e30f

// full-wave min via DPP (6 VALU ops), result broadcast via readlane(63)
__device__ __forceinline__ float wave_min_all(float x) {
  const int BI = __builtin_bit_cast(int, BIGF);
  int v = __builtin_bit_cast(int, x);
#define MIN_STEP(ctrl)                                                        \
  {                                                                           \
    int t_ = __builtin_amdgcn_update_dpp(BI, v, ctrl, 0xf, 0xf, false);       \
    v = __builtin_bit_cast(int, fminf(__builtin_bit_cast(float, v),           \
                                      __builtin_bit_cast(float, t_)));        \
  }
  MIN_STEP(0x111)  // row_shr:1
  MIN_STEP(0x112)  // row_shr:2
  MIN_STEP(0x114)  // row_shr:4
  MIN_STEP(0x118)  // row_shr:8
  MIN_STEP(0x142)  // row_bcast:15
  MIN_STEP(0x143)  // row_bcast:31
#undef MIN_STEP
  return __builtin_bit_cast(float, __builtin_amdgcn_readlane(v, 63));
}

__device__ __forceinline__ float rdlane_f(float x, int l) {
  return __builtin_bit_cast(float, __builtin_amdgcn_readlane(__builtin_bit_cast(int, x), l));
}

// JV LSAP on cost^T [32 x 128], one wave per batch. Lane owns cols 2*lane, 2*lane+1.
// All state in registers; cost row in LDS (stride 129 = conflict-free).
__global__ __launch_bounds__(64) void lsap_kernel(const float* __restrict__ cost,
                                                  float* __restrict__ out)
{
  const int b = blockIdx.x;
  const int lane = threadIdx.x;
  __shared__ float cTs[M_ * 129];

#pragma unroll 4
  for (int t = 0; t < 16; ++t) {
    int e = t * 256 + lane * 4;
    float4 v4 = *(const float4*)&cost[b * 4096 + e];
    int n = e >> 5, m = e & 31;
    cTs[(m + 0) * 129 + n] = v4.x;
    cTs[(m + 1) * 129 + n] = v4.y;
    cTs[(m + 2) * 129 + n] = v4.z;
    cTs[(m + 3) * 129 + n] = v4.w;
  }
  __syncthreads();

  float u_reg = 0.f;      // u[lane], lane<32
  int c4r = -1;           // col4row[lane], lane<32
  float v0 = 0.f, v1 = 0.f;   // v[2*lane], v[2*lane+1]
  int r40 = -1, r41 = -1;     // row4col

  for (int cur = 0; cur < M_; ++cur) {
    float sh0 = BIGF, sh1 = BIGF;
    int p0 = -1, p1 = -1;
    bool sc0 = false, sc1 = false;
    unsigned srmask = 0u;
    int i = cur, sink = -1;
    float minVal = 0.f;

    while (sink < 0) {
      srmask |= 1u << i;
      float ui = rdlane_f(u_reg, i);
      float cc0 = cTs[i * 129 + 2 * lane];
      float cc1 = cTs[i * 129 + 2 * lane + 1];
      // match jnp associativity: ((minVal + c) - u[i]) - v
      float d0 = ((minVal + cc0) - ui) - v0;
      float d1 = ((minVal + cc1) - ui) - v1;
      if (!sc0 && d0 < sh0) { sh0 = d0; p0 = i; }
      if (!sc1 && d1 < sh1) { sh1 = d1; p1 = i; }
      float m0 = sc0 ? BIGF : sh0;
      float m1 = sc1 ? BIGF : sh1;
      float mv = wave_min_all(fminf(m0, m1));
      unsigned long long bl0 = __ballot(m0 == mv);
      unsigned long long bl1 = __ballot(m1 == mv);
      int j0 = bl0 ? 2 * (int)__builtin_ctzll(bl0) : 0x7fffffff;
      int j1 = bl1 ? 2 * (int)__builtin_ctzll(bl1) + 1 : 0x7fffffff;
      int j = j0 < j1 ? j0 : j1;   // first-index tie-break
      minVal = mv;
      if (lane == (j >> 1)) { if (j & 1) sc1 = true; else sc0 = true; }
      int nxt = __builtin_amdgcn_readlane((j & 1) ? r41 : r40, j >> 1);
      if (nxt < 0) sink = j; else i = nxt;
    }

    // dual updates (before augmentation, scipy order)
    int jj = c4r < 0 ? 0 : c4r;
    float g0 = __shfl(sh0, jj >> 1);
    float g1 = __shfl(sh1, jj >> 1);
    float sj = (jj & 1) ? g1 : g0;
    if (lane < M_) {
      if (lane == cur) u_reg += minVal;
      else if ((srmask >> lane) & 1u) u_reg += minVal - sj;
    }
    if (sc0) v0 -= minVal - sh0;
    if (sc1) v1 -= minVal - sh1;

    // augment along path
    int j = sink;
    while (true) {
      int i2 = __builtin_amdgcn_readlane((j & 1) ? p1 : p0, j >> 1);
      if (lane == (j >> 1)) { if (j & 1) r41 = i2; else r40 = i2; }
      int tmp = __builtin_amdgcn_readlane(c4r, i2);
      if (lane == i2) c4r = j;
      if (i2 == cur) break;
      j = tmp;
    }
  }
  if (lane < M_) out[b * M_ + lane] = (float)c4r;
}

extern "C" void kernel_launch(void* const* d_in, const int* in_sizes, int n_in,
                              void* d_out, int out_size, void* d_ws, size_t ws_size,
                              hipStream_t stream)
{
  const float* obj  = (const float*)d_in[0];   // [8,128]
  const float* pred = (const float*)d_in[1];   // [8,128,65536]
  const float* gt   = (const float*)d_in[2];   // [8,32,65536]
  float* out = (float*)d_out;                  // cost 32768 || indices 256 (as float)

  float* xg    = (float*)d_ws;      // 32768
  float* sg    = xg + 32768;        // 32768
  float* spsum = sg + 32768;        // 1024
  float* ssum  = spsum + 1024;      // 1024
  float* gtsum = ssum + 1024;       // 256

  hipMemsetAsync(d_ws, 0, (size_t)(32768 * 2 + 1024 * 2 + 256) * sizeof(float), stream);
  cost_partial_kernel<<<dim3(KCHUNKS, B_), 512, 0, stream>>>(pred, gt, xg, sg, spsum, ssum, gtsum);
  finalize_kernel<<<dim3(32768 / 256), 256, 0, stream>>>(obj, xg, sg, spsum, ssum, gtsum, out);
  lsap_kernel<<<dim3(B_), 64, 0, stream>>>(out, out + 32768);
}

// Round 3
// 569.312 us; speedup vs baseline: 1.5104x; 1.0003x over previous
//
#include <hip/hip_runtime.h>
#include <hip/hip_bf16.h>

#define LOG2E 1.4426950408889634f
#define LN2   0.6931471805599453f

typedef __attribute__((ext_vector_type(8))) short short8;
typedef __attribute__((ext_vector_type(4))) float f32x4;

#define B_ 8
#define N_ 128
#define M_ 32
#define C_ 65536
#define KCHUNKS 64
#define KC (C_ / KCHUNKS)   // 1024
#define BK 64
#define AST 72              // LDS row stride in bf16 elems (144B: 16B-aligned)

__device__ __forceinline__ unsigned short f2bf(float f) {
  unsigned u = __builtin_bit_cast(unsigned, f);
  u += 0x7fffu + ((u >> 16) & 1u);   // RNE
  return (unsigned short)(u >> 16);
}
__device__ __forceinline__ unsigned pack_rne(float lo, float hi) {
  return (unsigned)f2bf(lo) | ((unsigned)f2bf(hi) << 16);
}
__device__ __forceinline__ unsigned pack_trunc(float lo, float hi) {  // exact for {0,1}
  unsigned ul = __builtin_bit_cast(unsigned, lo);
  unsigned uh = __builtin_bit_cast(unsigned, hi);
  return (uh & 0xFFFF0000u) | (ul >> 16);
}

// 512 blocks (64 k-chunks x 8 batches) x 256 threads, 2 blocks/CU.
// Fused: pred tile -> x,sigmoid,softplus -> bf16 LDS -> MFMA vs gt tile.
// NO atomics: every block writes its partials to a private ws slice.
__global__ __launch_bounds__(256, 2) void cost_partial_kernel(
    const float* __restrict__ pred, const float* __restrict__ gt,
    float* __restrict__ xg_part, float* __restrict__ sg_part,
    float* __restrict__ sp_part, float* __restrict__ ss_part,
    float* __restrict__ gts_part)
{
  __shared__ unsigned short As[256 * AST];  // rows 0..127: x, 128..255: sigmoid
  __shared__ unsigned short Bt[32 * AST];   // gt tile
  const int kc = blockIdx.x, b = blockIdx.y;
  const int tid = threadIdx.x;
  const int grp = tid >> 4, gl = tid & 15;   // pred: 16 rows/pass, 16 thr/row
  const int grow = tid >> 3, gh = tid & 7;   // gt: 32 rows, 8 thr/row
  const int wave = tid >> 6, lane = tid & 63;
  const int quad = lane >> 4, lcol = lane & 15;
  const int c0 = kc * KC;
  const int slab = kc * B_ + b;              // this block's partial slot

  const float* predB = pred + (size_t)b * N_ * C_ + c0;
  const float* gtB   = gt   + (size_t)b * M_ * C_ + (size_t)grow * C_ + c0;

  float spr[8], sr[8], gtacc = 0.f;
#pragma unroll
  for (int r = 0; r < 8; ++r) { spr[r] = 0.f; sr[r] = 0.f; }

  f32x4 acc[4][2];
#pragma unroll
  for (int rt = 0; rt < 4; ++rt)
#pragma unroll
    for (int ct = 0; ct < 2; ++ct)
      acc[rt][ct] = (f32x4){0.f, 0.f, 0.f, 0.f};

  for (int ks = 0; ks < KC / BK; ++ks) {
    const int cb = ks * BK;
    float4 p[8];
#pragma unroll
    for (int r = 0; r < 8; ++r)
      p[r] = *(const float4*)(predB + (size_t)(r * 16 + grp) * C_ + cb + gl * 4);
    float4 g0 = *(const float4*)(gtB + cb + gh * 4);
    float4 g1 = *(const float4*)(gtB + cb + (gh + 8) * 4);

#pragma unroll
    for (int r = 0; r < 8; ++r) {
      const int row = r * 16 + grp;
      float xs[4] = {p[r].x, p[r].y, p[r].z, p[r].w};
      float ss[4];
#pragma unroll
      for (int e = 0; e < 4; ++e) {
        float x = xs[e];
        float t = fminf(fmaxf(x * LOG2E, -80.f), 80.f);
        float e2 = __builtin_amdgcn_exp2f(t);
        float z = 1.f + e2;
        float s = e2 * __builtin_amdgcn_rcpf(z);
        spr[r] += __builtin_amdgcn_logf(z) * LN2;   // log1p(exp(x))
        sr[r]  += s;
        ss[e] = s;
      }
      *(uint2*)&As[row * AST + gl * 4] =
          (uint2){pack_rne(xs[0], xs[1]), pack_rne(xs[2], xs[3])};
      *(uint2*)&As[(N_ + row) * AST + gl * 4] =
          (uint2){pack_rne(ss[0], ss[1]), pack_rne(ss[2], ss[3])};
    }
    gtacc += g0.x + g0.y + g0.z + g0.w + g1.x + g1.y + g1.z + g1.w;
    *(uint2*)&Bt[grow * AST + gh * 4] =
        (uint2){pack_trunc(g0.x, g0.y), pack_trunc(g0.z, g0.w)};
    *(uint2*)&Bt[grow * AST + (gh + 8) * 4] =
        (uint2){pack_trunc(g1.x, g1.y), pack_trunc(g1.z, g1.w)};
    __syncthreads();

#pragma unroll
    for (int k0 = 0; k0 < BK; k0 += 32) {
      const int koff = k0 + quad * 8;
      short8 bf0 = *(const short8*)&Bt[lcol * AST + koff];
      short8 bf1 = *(const short8*)&Bt[(16 + lcol) * AST + koff];
#pragma unroll
      for (int rt = 0; rt < 4; ++rt) {
        short8 af = *(const short8*)&As[(wave * 64 + rt * 16 + lcol) * AST + koff];
        acc[rt][0] = __builtin_amdgcn_mfma_f32_16x16x32_bf16(af, bf0, acc[rt][0], 0, 0, 0);
        acc[rt][1] = __builtin_amdgcn_mfma_f32_16x16x32_bf16(af, bf1, acc[rt][1], 0, 0, 0);
      }
    }
    __syncthreads();
  }

  // per-row sums: 16 consecutive lanes share a pred row
#pragma unroll
  for (int r = 0; r < 8; ++r) {
    float v1 = spr[r], v2 = sr[r];
#pragma unroll
    for (int off = 1; off < 16; off <<= 1) {
      v1 += __shfl_xor(v1, off);
      v2 += __shfl_xor(v2, off);
    }
    if (gl == 0) {
      sp_part[slab * N_ + r * 16 + grp] = v1;
      ss_part[slab * N_ + r * 16 + grp] = v2;
    }
  }
  gtacc += __shfl_xor(gtacc, 1);
  gtacc += __shfl_xor(gtacc, 2);
  gtacc += __shfl_xor(gtacc, 4);
  if (gh == 0) gts_part[slab * M_ + grow] = gtacc;

  // GEMM partials, plain stores: C/D layout col=lane&15, row=(lane>>4)*4+reg
#pragma unroll
  for (int rt = 0; rt < 4; ++rt)
#pragma unroll
    for (int ct = 0; ct < 2; ++ct)
#pragma unroll
      for (int reg = 0; reg < 4; ++reg) {
        int orow = wave * 64 + rt * 16 + quad * 4 + reg;   // 0..255
        int ocol = ct * 16 + lcol;
        float v = acc[rt][ct][reg];
        if (orow < N_) xg_part[(slab * N_ + orow) * M_ + ocol] = v;
        else           sg_part[(slab * N_ + (orow - N_)) * M_ + ocol] = v;
      }
}

__global__ void finalize_kernel(const float* __restrict__ obj,
    const float* __restrict__ xg_part, const float* __restrict__ sg_part,
    const float* __restrict__ sp_part, const float* __restrict__ ss_part,
    const float* __restrict__ gts_part, float* __restrict__ cost)
{
  int idx = blockIdx.x * blockDim.x + threadIdx.x;  // [0, 32768)
  int b = idx >> 12;
  int n = (idx >> 5) & 127;
  int m = idx & 31;
  float xa = 0.f, sa = 0.f, spa = 0.f, ssa = 0.f, ga = 0.f;
#pragma unroll 4
  for (int kc = 0; kc < KCHUNKS; ++kc) {
    int slab = kc * B_ + b;
    xa  += xg_part[(slab * N_ + n) * M_ + m];
    sa  += sg_part[(slab * N_ + n) * M_ + m];
    spa += sp_part[slab * N_ + n];
    ssa += ss_part[slab * N_ + n];
    ga  += gts_part[slab * M_ + m];
  }
  float o = obj[b * N_ + n];
  float t = fminf(fmaxf(o * LOG2E, -80.f), 80.f);
  float e2 = __builtin_amdgcn_exp2f(t);
  float sig = e2 * __builtin_amdgcn_rcpf(1.f + e2);
  float bce = (spa - xa) * (1.0f / (float)C_);
  float dice = 1.f - (2.f * sa + 1.f) / (ssa + ga + 1.f);
  cost[idx] = -2.f * sig + 5.f * bce + 5.f * dice;
}

#define BIGF 1e30f

// full-wave min via DPP (6 VALU ops), result broadcast via readlane(63)
__device__ __forceinline__ float wave_min_all(float x) {
  const int BI = __builtin_bit_cast(int, BIGF);
  int v = __builtin_bit_cast(int, x);
#define MIN_STEP(ctrl)                                                        \
  {                                                                           \
    int t_ = __builtin_amdgcn_update_dpp(BI, v, ctrl, 0xf, 0xf, false);       \
    v = __builtin_bit_cast(int, fminf(__builtin_bit_cast(float, v),           \
                                      __builtin_bit_cast(float, t_)));        \
  }
  MIN_STEP(0x111)  // row_shr:1
  MIN_STEP(0x112)  // row_shr:2
  MIN_STEP(0x114)  // row_shr:4
  MIN_STEP(0x118)  // row_shr:8
  MIN_STEP(0x142)  // row_bcast:15
  MIN_STEP(0x143)  // row_bcast:31
#undef MIN_STEP
  return __builtin_bit_cast(float, __builtin_amdgcn_readlane(v, 63));
}

__device__ __forceinline__ float rdlane_f(float x, int l) {
  return __builtin_bit_cast(float, __builtin_amdgcn_readlane(__builtin_bit_cast(int, x), l));
}

// JV LSAP on cost^T [32 x 128], one wave per batch. Lane owns cols 2*lane, 2*lane+1.
// All state in registers; cost in LDS (stride 129 = conflict-free).
__global__ __launch_bounds__(64) void lsap_kernel(const float* __restrict__ cost,
                                                  float* __restrict__ out)
{
  const int b = blockIdx.x;
  const int lane = threadIdx.x;
  __shared__ float cTs[M_ * 129];

#pragma unroll 4
  for (int t = 0; t < 16; ++t) {
    int e = t * 256 + lane * 4;
    float4 v4 = *(const float4*)&cost[b * 4096 + e];
    int n = e >> 5, m = e & 31;
    cTs[(m + 0) * 129 + n] = v4.x;
    cTs[(m + 1) * 129 + n] = v4.y;
    cTs[(m + 2) * 129 + n] = v4.z;
    cTs[(m + 3) * 129 + n] = v4.w;
  }
  __syncthreads();

  float u_reg = 0.f;      // u[lane], lane<32
  int c4r = -1;           // col4row[lane], lane<32
  float v0 = 0.f, v1 = 0.f;   // v[2*lane], v[2*lane+1]
  int r40 = -1, r41 = -1;     // row4col

  for (int cur = 0; cur < M_; ++cur) {
    float sh0 = BIGF, sh1 = BIGF;
    int p0 = -1, p1 = -1;
    bool sc0 = false, sc1 = false;
    unsigned srmask = 0u;
    int i = cur, sink = -1;
    float minVal = 0.f;

    while (sink < 0) {
      srmask |= 1u << i;
      float ui = rdlane_f(u_reg, i);
      float cc0 = cTs[i * 129 + 2 * lane];
      float cc1 = cTs[i * 129 + 2 * lane + 1];
      // match jnp associativity: ((minVal + c) - u[i]) - v
      float d0 = ((minVal + cc0) - ui) - v0;
      float d1 = ((minVal + cc1) - ui) - v1;
      if (!sc0 && d0 < sh0) { sh0 = d0; p0 = i; }
      if (!sc1 && d1 < sh1) { sh1 = d1; p1 = i; }
      float m0 = sc0 ? BIGF : sh0;
      float m1 = sc1 ? BIGF : sh1;
      float mv = wave_min_all(fminf(m0, m1));
      unsigned long long bl0 = __ballot(m0 == mv);
      unsigned long long bl1 = __ballot(m1 == mv);
      int j0 = bl0 ? 2 * (int)__builtin_ctzll(bl0) : 0x7fffffff;
      int j1 = bl1 ? 2 * (int)__builtin_ctzll(bl1) + 1 : 0x7fffffff;
      int j = j0 < j1 ? j0 : j1;   // first-index tie-break
      minVal = mv;
      if (lane == (j >> 1)) { if (j & 1) sc1 = true; else sc0 = true; }
      int nxt = __builtin_amdgcn_readlane((j & 1) ? r41 : r40, j >> 1);
      if (nxt < 0) sink = j; else i = nxt;
    }

    // dual updates (before augmentation, scipy order)
    int jj = c4r < 0 ? 0 : c4r;
    float g0 = __shfl(sh0, jj >> 1);
    float g1 = __shfl(sh1, jj >> 1);
    float sj = (jj & 1) ? g1 : g0;
    if (lane < M_) {
      if (lane == cur) u_reg += minVal;
      else if ((srmask >> lane) & 1u) u_reg += minVal - sj;
    }
    if (sc0) v0 -= minVal - sh0;
    if (sc1) v1 -= minVal - sh1;

    // augment along path
    int j = sink;
    while (true) {
      int i2 = __builtin_amdgcn_readlane((j & 1) ? p1 : p0, j >> 1);
      if (lane == (j >> 1)) { if (j & 1) r41 = i2; else r40 = i2; }
      int tmp = __builtin_amdgcn_readlane(c4r, i2);
      if (lane == i2) c4r = j;
      if (i2 == cur) break;
      j = tmp;
    }
  }
  if (lane < M_) out[b * M_ + lane] = (float)c4r;
}

extern "C" void kernel_launch(void* const* d_in, const int* in_sizes, int n_in,
                              void* d_out, int out_size, void* d_ws, size_t ws_size,
                              hipStream_t stream)
{
  const float* obj  = (const float*)d_in[0];   // [8,128]
  const float* pred = (const float*)d_in[1];   // [8,128,65536]
  const float* gt   = (const float*)d_in[2];   // [8,32,65536]
  float* out = (float*)d_out;                  // cost 32768 || indices 256 (as float)

  // per-(kc,b) partial slabs — no atomics, no memset needed
  float* xg_part  = (float*)d_ws;                       // 64*8*128*32 = 2,097,152
  float* sg_part  = xg_part + (size_t)KCHUNKS * B_ * N_ * M_;
  float* sp_part  = sg_part + (size_t)KCHUNKS * B_ * N_ * M_;  // 64*8*128
  float* ss_part  = sp_part + (size_t)KCHUNKS * B_ * N_;
  float* gts_part = ss_part + (size_t)KCHUNKS * B_ * N_;       // 64*8*32

  cost_partial_kernel<<<dim3(KCHUNKS, B_), 256, 0, stream>>>(
      pred, gt, xg_part, sg_part, sp_part, ss_part, gts_part);
  finalize_kernel<<<dim3(32768 / 256), 256, 0, stream>>>(
      obj, xg_part, sg_part, sp_part, ss_part, gts_part, out);
  lsap_kernel<<<dim3(B_), 64, 0, stream>>>(out, out + 32768);
}